// Round 8
// baseline (33.688 us; speedup 1.0000x reference)
//
#include <hip/hip_runtime.h>
#include <math.h>

#define BB 32
#define LL 512
#define DD 1024
#define TT 256
#define NK 136393              // kept (s,e) pairs per batch
#define NK_LIN 131273          // off(502)
#define S_LIN 502
#define NEG_BIG  -3.0e38f      // finite stand-in for -inf
#define NEG_MASK -1.0e30f      // finite stand-in for masked logits
#define P_TOT (BB * NK)        // 4364576 pairs
#define GEMV_BLOCKS 4096       // BB*LL/4
#define FILL_BLOCKS 16384      // LL*BB (one per output row)
#define MEGA_BLOCKS 20480      // 5*4096: stripe 1 gemv : 4 fill

typedef float f4v __attribute__((ext_vector_type(4)));
typedef float f2v __attribute__((ext_vector_type(2)));

__device__ __forceinline__ int off_s(int s) {
    return (s <= S_LIN) ? s * (s + 21) / 2 : NK_LIN + (s - S_LIN) * LL;
}

// ---- d1 (mega): striped {GEMV | row-fill}, one dispatch -------------------
// GEMV block: wave per row, logits -> slp/elp/mlp (L2-resident intermediates).
// Fill block (one per output row): prefix scores e<s = const NEG_BIG float4
// stream; all bounds {s,e} from lane id. ~20 VALU per 48B (vs ~175 in R7).
__global__ __launch_bounds__(256) void mega_kernel(
    const float* __restrict__ text, const float* __restrict__ W,
    const float* __restrict__ bias, const int* __restrict__ mask,
    float* __restrict__ out,
    float* __restrict__ slp, float* __restrict__ elp, float* __restrict__ mlp)
{
    const int id = blockIdx.x;
    const int q5 = id / 5;                        // magic-mul
    if (id - q5 * 5 == 0) {
        // ---- GEMV: rows 4*q5 .. 4*q5+3, one wave each ----
        const int wid  = threadIdx.x >> 6;
        const int lane = threadIdx.x & 63;
        const int row  = q5 * 4 + wid;            // row = b*L + l
        const f4v* t4 = (const f4v*)(text + (size_t)row * DD);
        const f4v* w4 = (const f4v*)W;
        float a0 = 0.f, a1 = 0.f, a2 = 0.f;
#pragma unroll
        for (int j = 0; j < 4; ++j) {
            const int fi = lane + j * 64;
            f4v v  = t4[fi];                      // coalesced 1KB/instr/wave
            f4v w0 = w4[fi * 3 + 0];              // L1-hot
            f4v w1 = w4[fi * 3 + 1];
            f4v w2 = w4[fi * 3 + 2];
            a0 += v.x * w0.x;  a1 += v.x * w0.y;  a2 += v.x * w0.z;
            a0 += v.y * w0.w;  a1 += v.y * w1.x;  a2 += v.y * w1.y;
            a0 += v.z * w1.z;  a1 += v.z * w1.w;  a2 += v.z * w2.x;
            a0 += v.w * w2.y;  a1 += v.w * w2.z;  a2 += v.w * w2.w;
        }
#pragma unroll
        for (int o = 32; o; o >>= 1) {
            a0 += __shfl_down(a0, o);
            a1 += __shfl_down(a1, o);
            a2 += __shfl_down(a2, o);
        }
        if (lane == 0) {
            const int m = mask[row];
            slp[row] = (m == 1) ? a0 + bias[0] : NEG_MASK;
            elp[row] = (m == 1) ? a1 + bias[1] : NEG_MASK;
            mlp[row] = (m == 1) ? a2 + bias[2] : NEG_MASK;
        }
        return;
    }

    // ---- FILL: output row (b, s). Uniform s -> no per-position inversion.
    const int fid = id - q5 - 1;                  // 0..16383
    const int b = fid >> 9;
    const int s = fid & 511;
    const int rowlen = (s <= S_LIN) ? (s + 11) : LL;   // min(LL, s+11)
    const int flat0 = b * NK + off_s(s);          // row's first pair index
    const int t = threadIdx.x;
    const float sf = (float)s;

    // prefix scores [0, s): constant NEG_BIG, f4v body + scalar head/rem
    const int a = (4 - (flat0 & 3)) & 3;
    const int head = min(s, a);
    const int nb = (s - head) >> 2;               // <= 127
    const int rem = (s - head) & 3;
    if (t < nb) {
        f4v neg = {NEG_BIG, NEG_BIG, NEG_BIG, NEG_BIG};
        __builtin_nontemporal_store(neg, (f4v*)(out + flat0 + head + 4 * t));
    } else if (t >= 248 && t < 248 + head) {
        __builtin_nontemporal_store(NEG_BIG, out + flat0 + (t - 248));
    } else if (t >= 252 && t < 252 + rem) {
        __builtin_nontemporal_store(NEG_BIG, out + flat0 + head + 4 * nb + (t - 252));
    }

    // bounds [0, rowlen): {s, e}, 8B-aligned f2v
    f2v* bp = (f2v*)(out + (size_t)P_TOT);
    if (t < rowlen) {
        f2v v = {sf, (float)t};
        __builtin_nontemporal_store(v, &bp[flat0 + t]);
    }
    const int t2 = t + 256;
    if (t2 < rowlen) {
        f2v v = {sf, (float)t2};
        __builtin_nontemporal_store(v, &bp[flat0 + t2]);
    }
}

// ---- d2 (tail): the <=11 data-dependent positions per row ----------------
// One block per batch; thread t = row s. Writes ALL of [s, rowlen) exactly
// once (disjoint from fill's [0,s) prefix) -> no ordering hazard with d1.
__global__ __launch_bounds__(512) void tail_kernel(
    const float* __restrict__ slp, const float* __restrict__ elp,
    const float* __restrict__ mlp, const int* __restrict__ mask,
    const int* __restrict__ tmap, float* __restrict__ out)
{
    const int b = blockIdx.x;
    const int t = threadIdx.x;                    // = s
    __shared__ unsigned char tsl[LL], tel[LL];
    tsl[t] = 0; tel[t] = 0;
    __syncthreads();
    if (t < TT) {
        int s0 = tmap[((size_t)b * TT + t) * 2 + 0];
        int e0 = tmap[((size_t)b * TT + t) * 2 + 1] - 1;
        s0 = min(max(s0, 0), LL - 1);
        e0 = min(max(e0, 0), LL - 1);
        tsl[s0] = 1;                              // benign race: all write 1
        tel[e0] = 1;
    }
    __syncthreads();

    const int s = t;
    const int base = b * LL;
    const int rowlen = (s <= S_LIN) ? (s + 11) : LL;
    const int flat0 = b * NK + off_s(s);
    const bool fss = (s > 0) && tsl[s] && (mask[base + s] == 1);
    const float sv = fss ? slp[base + s] : 0.f;
    float w = 0.f;
    for (int e = s; e < rowlen; ++e) {            // <= 11 iterations
        float v = NEG_BIG;
        if (fss) {
            w += mlp[base + e];                   // window sum, L2-hot
            if (tel[e]) {                         // e >= s > 0
                v = sv + elp[base + e] + w;
                if (v < -1.0e29f) v = NEG_BIG;    // masked row -> -inf in ref
            }
        }
        out[flat0 + e] = v;
    }
}

extern "C" void kernel_launch(void* const* d_in, const int* in_sizes, int n_in,
                              void* d_out, int out_size, void* d_ws, size_t ws_size,
                              hipStream_t stream) {
    const float* text = (const float*)d_in[0];   // (B,L,D) f32
    const int*   mask = (const int*)d_in[1];     // (B,L) i32
    const int*   tmap = (const int*)d_in[2];     // (B,T,2) i32
    const float* W    = (const float*)d_in[3];   // (D,3) f32
    const float* bias = (const float*)d_in[4];   // (3,) f32
    float* out = (float*)d_out;

    float* slp = (float*)d_ws;                   // B*L each
    float* elp = slp + (size_t)BB * LL;
    float* mlp = elp + (size_t)BB * LL;

    mega_kernel<<<MEGA_BLOCKS, 256, 0, stream>>>(text, W, bias, mask, out,
                                                 slp, elp, mlp);
    tail_kernel<<<BB, 512, 0, stream>>>(slp, elp, mlp, mask, tmap, out);
}

// Round 9
// 28.532 us; speedup vs baseline: 1.1807x; 1.1807x over previous
//
#include <hip/hip_runtime.h>
#include <math.h>

#define BB 32
#define LL 512
#define DD 1024
#define TT 256
#define NK 136393              // kept (s,e) pairs per batch
#define NK_LIN 131273          // off(502)
#define S_LIN 502
#define NEG_BIG  -3.0e38f      // finite stand-in for -inf
#define NEG_MASK -1.0e30f      // finite stand-in for masked logits
#define P_TOT (BB * NK)        // 4364576 pairs
#define SC4 (P_TOT / 4)        // 1091144 score float4s
#define GEMV_BLOCKS 4096       // BB*LL/4 rows / 4 per block
#define MEMSET_BLOCKS ((SC4 + 255) / 256)    // 4263
#define BCHUNKS ((NK + 255) / 256)           // 533 pattern chunks
#define BGROUPS 2                            // 16 batches per group
#define BOUNDS_BLOCKS (BCHUNKS * BGROUPS)    // 1066
#define PERIOD 9
#define QMAX 1066
#define MEGA_BLOCKS (PERIOD * QMAX)          // 9594

typedef float f4v __attribute__((ext_vector_type(4)));
typedef float f2v __attribute__((ext_vector_type(2)));

__device__ __forceinline__ int off_s(int s) {
    return (s <= S_LIN) ? s * (s + 21) / 2 : NK_LIN + (s - S_LIN) * LL;
}

// ---- d1 (mega): striped 4:4:1 {GEMV | score-memset | bounds-fanout} ------
__global__ __launch_bounds__(256) void mega_kernel(
    const float* __restrict__ text, const float* __restrict__ W,
    const float* __restrict__ bias, const int* __restrict__ mask,
    float* __restrict__ out,
    float* __restrict__ slp, float* __restrict__ elp, float* __restrict__ mlp)
{
    const int id = blockIdx.x;
    const int q  = id / PERIOD;                   // magic-mul
    const int r  = id - q * PERIOD;

    if (r < 4) {
        // ---- GEMV: logits = text @ W + b, wave per row ----
        const int g = q * 4 + r;
        if (g >= GEMV_BLOCKS) return;
        const int wid  = threadIdx.x >> 6;
        const int lane = threadIdx.x & 63;
        const int row  = g * 4 + wid;             // row = b*L + l
        const f4v* t4 = (const f4v*)(text + (size_t)row * DD);
        const f4v* w4 = (const f4v*)W;
        float a0 = 0.f, a1 = 0.f, a2 = 0.f;
#pragma unroll
        for (int j = 0; j < 4; ++j) {
            const int fi = lane + j * 64;
            f4v v  = t4[fi];                      // coalesced 1KB/instr/wave
            f4v w0 = w4[fi * 3 + 0];              // L1-hot
            f4v w1 = w4[fi * 3 + 1];
            f4v w2 = w4[fi * 3 + 2];
            a0 += v.x * w0.x;  a1 += v.x * w0.y;  a2 += v.x * w0.z;
            a0 += v.y * w0.w;  a1 += v.y * w1.x;  a2 += v.y * w1.y;
            a0 += v.z * w1.z;  a1 += v.z * w1.w;  a2 += v.z * w2.x;
            a0 += v.w * w2.y;  a1 += v.w * w2.z;  a2 += v.w * w2.w;
        }
#pragma unroll
        for (int o = 32; o; o >>= 1) {
            a0 += __shfl_down(a0, o);
            a1 += __shfl_down(a1, o);
            a2 += __shfl_down(a2, o);
        }
        if (lane == 0) {
            const int m = mask[row];
            slp[row] = (m == 1) ? a0 + bias[0] : NEG_MASK;
            elp[row] = (m == 1) ? a1 + bias[1] : NEG_MASK;
            mlp[row] = (m == 1) ? a2 + bias[2] : NEG_MASK;
        }
        return;
    }

    if (r < 8) {
        // ---- Score memset: pure constant f4v stream, zero math ----
        const int m = q * 4 + (r - 4);
        if (m >= MEMSET_BLOCKS) return;
        const int i = m * 256 + threadIdx.x;
        if (i < SC4) {
            f4v neg = {NEG_BIG, NEG_BIG, NEG_BIG, NEG_BIG};
            ((f4v*)out)[i] = neg;
        }
        return;
    }

    // ---- Bounds fan-out: invert once, store {s,e} to 16 batches ----
    // Pattern is batch-invariant; per-instr stores are lane-contiguous 8B.
    if (q >= BOUNDS_BLOCKS) return;
    const int c = q % BCHUNKS;                    // pattern chunk
    const int g = q / BCHUNKS;                    // batch group (16 each)
    const int p = c * 256 + threadIdx.x;          // pattern position
    if (p >= NK) return;
    int s, e;
    if (p >= NK_LIN) {
        const int rr = p - NK_LIN;
        s = S_LIN + (rr >> 9);
        e = rr & 511;
    } else {
        float f = sqrtf(8.0f * (float)p + 441.0f);
        s = (int)((f - 21.0f) * 0.5f);
        if (s < 0) s = 0;
        if (s > 501) s = 501;
        while ((s + 1) * (s + 22) / 2 <= p) ++s;
        while (s * (s + 21) / 2 > p) --s;
        e = p - s * (s + 21) / 2;
    }
    f2v v = {(float)s, (float)e};
    f2v* bp = (f2v*)(out + (size_t)P_TOT);
#pragma unroll
    for (int j = 0; j < 16; ++j) {
        const int b = g * 16 + j;
        bp[(size_t)b * NK + p] = v;
    }
}

// ---- d2: scatter valid scores (~2.2K per batch), overwrites memset -------
__global__ __launch_bounds__(512) void scatter_kernel(
    const float* __restrict__ slp, const float* __restrict__ elp,
    const float* __restrict__ mlp, const int* __restrict__ mask,
    const int* __restrict__ tmap, float* __restrict__ out)
{
    const int b = blockIdx.x;
    const int t = threadIdx.x;
    __shared__ float sl[LL], el[LL], ml[LL];
    __shared__ unsigned char tsl[LL], tel[LL];

    tsl[t] = 0; tel[t] = 0;
    const int idx = b * LL + t;
    sl[t] = slp[idx]; el[t] = elp[idx]; ml[t] = mlp[idx];
    __syncthreads();
    if (t < TT) {
        int s0 = tmap[((size_t)b * TT + t) * 2 + 0];
        int e0 = tmap[((size_t)b * TT + t) * 2 + 1] - 1;
        s0 = min(max(s0, 0), LL - 1);
        e0 = min(max(e0, 0), LL - 1);
        tsl[s0] = 1;                              // benign race: all write 1
        tel[e0] = 1;
    }
    __syncthreads();

    const int s = t;
    if (s > 0 && tsl[s] && mask[idx] == 1) {
        const size_t obase = (size_t)b * NK + off_s(s);
        const float sv = sl[s];
        const int emax = min(LL - 1, s + 10);
        float w = 0.f;
        for (int e = s; e <= emax; ++e) {
            w += ml[e];
            if (tel[e]) {                         // e >= s >= 1, so e != 0
                float sc = sv + el[e] + w;
                if (sc < -1.0e29f) sc = NEG_BIG;  // masked -> -inf in ref
                out[obase + e] = sc;
            }
        }
    }
}

extern "C" void kernel_launch(void* const* d_in, const int* in_sizes, int n_in,
                              void* d_out, int out_size, void* d_ws, size_t ws_size,
                              hipStream_t stream) {
    const float* text = (const float*)d_in[0];   // (B,L,D) f32
    const int*   mask = (const int*)d_in[1];     // (B,L) i32
    const int*   tmap = (const int*)d_in[2];     // (B,T,2) i32
    const float* W    = (const float*)d_in[3];   // (D,3) f32
    const float* bias = (const float*)d_in[4];   // (3,) f32
    float* out = (float*)d_out;

    float* slp = (float*)d_ws;                   // B*L each
    float* elp = slp + (size_t)BB * LL;
    float* mlp = elp + (size_t)BB * LL;

    mega_kernel<<<MEGA_BLOCKS, 256, 0, stream>>>(text, W, bias, mask, out,
                                                 slp, elp, mlp);
    scatter_kernel<<<BB, 512, 0, stream>>>(slp, elp, mlp, mask, tmap, out);
}